// Round 1
// baseline (17832.487 us; speedup 1.0000x reference)
//
#include <hip/hip_runtime.h>
#include <math.h>

// Problem dims
#define BB   64
#define TT   512
#define LL   256
#define HIDD 256
#define KEYDD 128
#define VALDD 128
#define VOC  4096

__device__ __forceinline__ float sigm(float x){ return 1.0f/(1.0f+__expf(-x)); }

// One-time weight transpose into workspace:
// W1T [640][1024]: k<384 -> W_ih1[j][k] (cols: emb 0..255, ctx 256..383), k>=384 -> W_hh1[j][k-384]
// W2T [384][512]:  k<256 -> W_ih2[j][k] (h1), k>=256 -> W_hh2[j][k-256] (h2)
__global__ void transpose_w(const float* __restrict__ Wi1, const float* __restrict__ Wh1,
                            const float* __restrict__ Wi2, const float* __restrict__ Wh2,
                            float* __restrict__ W1T, float* __restrict__ W2T){
  int idx = blockIdx.x*blockDim.x + threadIdx.x;
  if (idx < 640*1024){
    int k = idx >> 10, j = idx & 1023;
    W1T[idx] = (k < 384) ? Wi1[j*384 + k] : Wh1[j*256 + (k-384)];
  }
  if (idx < 384*512){
    int k = idx >> 9, j = idx & 511;
    W2T[idx] = (k < 256) ? Wi2[j*256 + k] : Wh2[j*128 + (k-256)];
  }
}

// Recurrence: one workgroup per batch element, 1024 threads, all state in LDS.
// Writes states[(b*LL+t)*256 + d] = concat(h2, ctx) for the final logits GEMM.
__global__ __launch_bounds__(1024) void rec_kernel(
    const float* __restrict__ key, const float* __restrict__ values,
    const int*   __restrict__ text, const float* __restrict__ emb,
    const float* __restrict__ W1T, const float* __restrict__ W2T,
    const float* __restrict__ bi1, const float* __restrict__ bh1,
    const float* __restrict__ bi2, const float* __restrict__ bh2,
    float* __restrict__ states)
{
  const int b   = blockIdx.x;
  const int tid = threadIdx.x;

  __shared__ float inp[384];        // [emb(256) | ctx(128)]
  __shared__ float hh[384];         // [h1(256) | h2(128)]
  __shared__ float c1s[256];
  __shared__ float c2s[128];
  __shared__ float g1[1024];
  __shared__ float g2[512];
  __shared__ float att[512];
  __shared__ float part[8*128];
  __shared__ float red[16];

  if (tid < 384) hh[tid] = 0.f;
  if (tid < 256) c1s[tid] = 0.f;
  if (tid < 128){ c2s[tid] = 0.f; inp[256+tid] = 0.f; }
  __syncthreads();

  for (int t = 0; t < LL; ++t){
    // ---- embedding lookup (teacher forcing)
    if (tid < 256){
      int row = text[b*LL + t];
      inp[tid] = emb[row*HIDD + tid];
    }
    __syncthreads();

    // ---- LSTM1 gates: g1[j] = b_ih1[j]+b_hh1[j] + sum_k W1T[k][j]*cat1[k]
    {
      float s = bi1[tid] + bh1[tid];
      const float* w = W1T + tid;
      #pragma unroll 8
      for (int k = 0; k < 384; ++k) s += w[k*1024] * inp[k];
      w += 384*1024;
      #pragma unroll 8
      for (int k = 0; k < 256; ++k) s += w[k*1024] * hh[k];
      g1[tid] = s;
    }
    __syncthreads();
    if (tid < 256){
      float gi = sigm(g1[tid]);
      float gf = sigm(g1[tid+256]);
      float gg = tanhf(g1[tid+512]);
      float go = sigm(g1[tid+768]);
      float c  = gf*c1s[tid] + gi*gg;
      c1s[tid] = c;
      hh[tid]  = go*tanhf(c);      // new h1
    }
    __syncthreads();

    // ---- LSTM2 gates: pair of threads per output j, halves of K=384
    {
      int j = tid >> 1, h = tid & 1;
      float s = 0.f;
      const float* w = W2T + j;
      int k0 = h*192;
      #pragma unroll 8
      for (int k = k0; k < k0+192; ++k) s += w[k*512] * hh[k];
      s += __shfl_xor(s, 1);
      if (h == 0) g2[j] = s + bi2[j] + bh2[j];
    }
    __syncthreads();
    if (tid < 128){
      float gi = sigm(g2[tid]);
      float gf = sigm(g2[tid+128]);
      float gg = tanhf(g2[tid+256]);
      float go = sigm(g2[tid+384]);
      float c  = gf*c2s[tid] + gi*gg;
      c2s[tid] = c;
      hh[256+tid] = go*tanhf(c);   // new h2
    }
    __syncthreads();

    // ---- attention energies: e[s] = key[b,s,:] . h2
    if (tid < 512){
      const float4* kp = reinterpret_cast<const float4*>(key + ((size_t)b*TT + tid)*KEYDD);
      const float4* hq = reinterpret_cast<const float4*>(hh + 256);
      float e = 0.f;
      #pragma unroll 8
      for (int k = 0; k < 32; ++k){
        float4 kv = kp[k]; float4 hv = hq[k];
        e += kv.x*hv.x + kv.y*hv.y + kv.z*hv.z + kv.w*hv.w;
      }
      att[tid] = e;
    }
    __syncthreads();

    // ---- softmax over 512 (wave reduce -> 8 partials -> combine)
    {
      float m = (tid < 512) ? att[tid] : -3.4e38f;
      #pragma unroll
      for (int off = 32; off > 0; off >>= 1) m = fmaxf(m, __shfl_xor(m, off));
      if (tid < 512 && (tid & 63) == 0) red[tid >> 6] = m;
      __syncthreads();
      float M = fmaxf(fmaxf(fmaxf(red[0],red[1]),fmaxf(red[2],red[3])),
                      fmaxf(fmaxf(red[4],red[5]),fmaxf(red[6],red[7])));
      float e = 0.f;
      if (tid < 512){ e = __expf(att[tid] - M); att[tid] = e; }
      float ssum = e;
      #pragma unroll
      for (int off = 32; off > 0; off >>= 1) ssum += __shfl_xor(ssum, off);
      if (tid < 512 && (tid & 63) == 0) red[8 + (tid >> 6)] = ssum;
      __syncthreads();
      float S = ((red[8]+red[9])+(red[10]+red[11]))+((red[12]+red[13])+(red[14]+red[15]));
      float inv = 1.0f / S;
      if (tid < 512) att[tid] *= inv;
    }
    __syncthreads();

    // ---- context: ctx[v] = sum_s att[s]*values[b,s,v]  (128 v x 8 s-chunks)
    {
      int v = tid & 127, ch = tid >> 7;
      const float* vp = values + ((size_t)b*TT + ch*64)*VALDD + v;
      float p = 0.f;
      #pragma unroll 8
      for (int s = 0; s < 64; ++s) p += att[ch*64 + s] * vp[(size_t)s*VALDD];
      part[ch*128 + v] = p;
    }
    __syncthreads();
    if (tid < 128){
      float cx = 0.f;
      #pragma unroll
      for (int ch = 0; ch < 8; ++ch) cx += part[ch*128 + tid];
      inp[256+tid] = cx;                           // ctx for next step's LSTM1
      size_t row = (size_t)b*LL + t;
      states[row*256 + tid]       = hh[256+tid];   // h2
      states[row*256 + 128 + tid] = cx;            // ctx
    }
    __syncthreads();
  }
}

// Final logits GEMM: C[n][v] = sum_d A[n][d]*Bm[v][d] + bias[v]
// A = states [16384][256], Bm = embedding [4096][256] (tied weights), C [16384][4096]
__global__ __launch_bounds__(256) void gemm_kernel(
    const float* __restrict__ A, const float* __restrict__ Bm,
    const float* __restrict__ bias, float* __restrict__ C)
{
  __shared__ float As[16][132];   // stride 132 floats = 528 B (16B-aligned rows, bank-spread)
  __shared__ float Bs[16][132];
  const int tid = threadIdx.x;
  const int tx = tid & 15, ty = tid >> 4;
  const int bn = blockIdx.x, bm = blockIdx.y;

  float acc[8][8];
  #pragma unroll
  for (int i = 0; i < 8; ++i)
    #pragma unroll
    for (int j = 0; j < 8; ++j) acc[i][j] = 0.f;

  const int r  = tid >> 1;
  const int ko = (tid & 1) * 8;
  const float* Ap = A  + ((size_t)(bm*128 + r))*256 + ko;
  const float* Bp = Bm + ((size_t)(bn*128 + r))*256 + ko;

  for (int k0 = 0; k0 < 256; k0 += 16){
    float4 a0 = *(const float4*)(Ap + k0);
    float4 a1 = *(const float4*)(Ap + k0 + 4);
    float4 b0 = *(const float4*)(Bp + k0);
    float4 b1 = *(const float4*)(Bp + k0 + 4);
    As[ko+0][r]=a0.x; As[ko+1][r]=a0.y; As[ko+2][r]=a0.z; As[ko+3][r]=a0.w;
    As[ko+4][r]=a1.x; As[ko+5][r]=a1.y; As[ko+6][r]=a1.z; As[ko+7][r]=a1.w;
    Bs[ko+0][r]=b0.x; Bs[ko+1][r]=b0.y; Bs[ko+2][r]=b0.z; Bs[ko+3][r]=b0.w;
    Bs[ko+4][r]=b1.x; Bs[ko+5][r]=b1.y; Bs[ko+6][r]=b1.z; Bs[ko+7][r]=b1.w;
    __syncthreads();
    #pragma unroll
    for (int k = 0; k < 16; ++k){
      float4 x0 = *(const float4*)&As[k][ty*8];
      float4 x1 = *(const float4*)&As[k][ty*8+4];
      float4 y0 = *(const float4*)&Bs[k][tx*8];
      float4 y1 = *(const float4*)&Bs[k][tx*8+4];
      float av[8] = {x0.x,x0.y,x0.z,x0.w,x1.x,x1.y,x1.z,x1.w};
      float bv[8] = {y0.x,y0.y,y0.z,y0.w,y1.x,y1.y,y1.z,y1.w};
      #pragma unroll
      for (int i = 0; i < 8; ++i)
        #pragma unroll
        for (int j = 0; j < 8; ++j) acc[i][j] += av[i]*bv[j];
    }
    __syncthreads();
  }

  const int c0 = bn*128 + tx*8;
  float bl[8];
  #pragma unroll
  for (int j = 0; j < 8; ++j) bl[j] = bias[c0 + j];
  #pragma unroll
  for (int i = 0; i < 8; ++i){
    size_t row = (size_t)(bm*128 + ty*8 + i);
    float4 o0 = make_float4(acc[i][0]+bl[0], acc[i][1]+bl[1], acc[i][2]+bl[2], acc[i][3]+bl[3]);
    float4 o1 = make_float4(acc[i][4]+bl[4], acc[i][5]+bl[5], acc[i][6]+bl[6], acc[i][7]+bl[7]);
    *(float4*)(C + row*4096 + c0)     = o0;
    *(float4*)(C + row*4096 + c0 + 4) = o1;
  }
}

extern "C" void kernel_launch(void* const* d_in, const int* in_sizes, int n_in,
                              void* d_out, int out_size, void* d_ws, size_t ws_size,
                              hipStream_t stream)
{
  const float* key    = (const float*)d_in[0];
  const float* values = (const float*)d_in[1];
  // d_in[2] = lens (unused by reference path)
  const int*   text   = (const int*)  d_in[3];
  const float* emb    = (const float*)d_in[4];
  const float* Wi1    = (const float*)d_in[5];
  const float* Wh1    = (const float*)d_in[6];
  const float* bi1    = (const float*)d_in[7];
  const float* bh1    = (const float*)d_in[8];
  const float* Wi2    = (const float*)d_in[9];
  const float* Wh2    = (const float*)d_in[10];
  const float* bi2    = (const float*)d_in[11];
  const float* bh2    = (const float*)d_in[12];
  const float* bout   = (const float*)d_in[13];

  // workspace layout (floats): states[16384*256] | W1T[640*1024] | W2T[384*512]  (~20.2 MB)
  float* states = (float*)d_ws;
  float* W1T    = states + (size_t)BB*LL*256;
  float* W2T    = W1T + 640*1024;

  transpose_w<<<2560, 256, 0, stream>>>(Wi1, Wh1, Wi2, Wh2, W1T, W2T);
  rec_kernel<<<BB, 1024, 0, stream>>>(key, values, text, emb, W1T, W2T,
                                      bi1, bh1, bi2, bh2, states);
  dim3 grid(VOC/128, (BB*LL)/128);
  gemm_kernel<<<grid, 256, 0, stream>>>(states, emb, bout, (float*)d_out);
}